// Round 6
// baseline (1030.679 us; speedup 1.0000x reference)
//
#include <hip/hip_runtime.h>
#include <stdint.h>

#define SEQ    2048
#define DMODEL 2048
#define NTOK   4096   // B*S
#define NHEAD  16
#define NKVH   4
#define HDIM   128
#define FFDIM  7168
#define FFH    3584   // FFDIM / 2 (MLP processed in two column halves to fit workspace)
#define QKVS   3072   // merged qkv row stride: q[0,2048) k[2048,2560) v[2560,3072)

typedef __bf16 bf16x8 __attribute__((ext_vector_type(8)));
typedef float  floatx4 __attribute__((ext_vector_type(4)));

__device__ __forceinline__ float bf2f(unsigned short u) {
  union { unsigned int i; float f; } v; v.i = ((unsigned int)u) << 16; return v.f;
}
__device__ __forceinline__ unsigned short f2bf(float f) {
  union { float f; unsigned int u; } v; v.f = f;
  unsigned int r = (v.u + 0x7FFFu + ((v.u >> 16) & 1u)) >> 16;
  return (unsigned short)r;
}
// 8 f32 elements (32B) from f32 memory, converted to 8 bf16 (16B)
__device__ __forceinline__ uint4 ld8f32(const float* p) {
  float4 a = *(const float4*)p, b = *(const float4*)(p + 4);
  union { unsigned short s[8]; uint4 v; } o;
  o.s[0] = f2bf(a.x); o.s[1] = f2bf(a.y); o.s[2] = f2bf(a.z); o.s[3] = f2bf(a.w);
  o.s[4] = f2bf(b.x); o.s[5] = f2bf(b.y); o.s[6] = f2bf(b.z); o.s[7] = f2bf(b.w);
  return o.v;
}

// async HBM->LDS, 16B per lane. LDS dest = wave-uniform base + lane*16 (linear!).
__device__ __forceinline__ void gload16(const unsigned short* g, unsigned short* l) {
  __builtin_amdgcn_global_load_lds(
      (const __attribute__((address_space(1))) unsigned int*)g,
      (__attribute__((address_space(3))) unsigned int*)l, 16, 0, 0);
}

// ---------------- fused attn-weight conversion + MoD counter zero ----------------
// blocks 0..2047: q rows; 2048..2559: k; 2560..3071: v; 3072..5119: o.
__global__ __launch_bounds__(256) void wconv_attn(
    const float* __restrict__ q, const float* __restrict__ k,
    const float* __restrict__ v, const float* __restrict__ o,
    unsigned short* __restrict__ wqkv, unsigned short* __restrict__ wo,
    int* __restrict__ cnt) {
  if (blockIdx.x == 0 && threadIdx.x == 0) *cnt = 0;
  const int r = blockIdx.x;
  const float* src;
  unsigned short* dst;
  if (r < 2048)      { src = q + (size_t)r * DMODEL;          dst = wqkv + (size_t)r * DMODEL; }
  else if (r < 2560) { src = k + (size_t)(r - 2048) * DMODEL; dst = wqkv + (size_t)r * DMODEL; }
  else if (r < 3072) { src = v + (size_t)(r - 2560) * DMODEL; dst = wqkv + (size_t)r * DMODEL; }
  else               { src = o + (size_t)(r - 3072) * DMODEL; dst = wo + (size_t)(r - 3072) * DMODEL; }
  const int c = threadIdx.x * 8;
  *(uint4*)(dst + c) = ld8f32(src + c);
}

// ---------------- fused gate+up conversion (dst: wg|wu contiguous) ---------------
// grid MUST be 2*FFH = 7168 blocks (one per dst row).
__global__ __launch_bounds__(256) void wconv_gu(
    const float* __restrict__ g, const float* __restrict__ u,
    unsigned short* __restrict__ dst, int hf) {
  const int r = blockIdx.x;  // 0..7167
  const float* src = (r < FFH) ? g + ((size_t)hf * FFH + r) * DMODEL
                               : u + ((size_t)hf * FFH + (r - FFH)) * DMODEL;
  const int c = threadIdx.x * 8;
  *(uint4*)(dst + (size_t)r * DMODEL + c) = ld8f32(src + c);
}

// strided conversion for down-proj K-slice: src [DMODEL][FFDIM], cols [koff,koff+FFH)
__global__ __launch_bounds__(256) void wconv_dn(const float* __restrict__ s,
                                                unsigned short* __restrict__ d, int koff) {
  const int r = blockIdx.x;  // 2048 rows
  const float* sp = s + (size_t)r * FFDIM + koff;
  unsigned short* dp = d + (size_t)r * FFH;
  for (int c = threadIdx.x * 8; c < FFH; c += 2048)
    *(uint4*)(dp + c) = ld8f32(sp + c);
}

// ======== GEMM core: 128x128 tile, BK=32, 4 waves, A bf16 / W bf16 ==============
// LDA/LDB row strides, KLEN loop length, KOFF column offset (for split-K).
#define GEMM_CORE_G(Aptr, Wptr, LDA, LDB, KLEN, KOFF)                            \
  __shared__ __align__(16) unsigned short As[128 * 32];                          \
  __shared__ __align__(16) unsigned short Bs[128 * 32];                          \
  const int tid  = threadIdx.x;                                                  \
  const int wave = tid >> 6, lane = tid & 63;                                    \
  const int quad = lane >> 4, l16 = lane & 15;                                   \
  const int row0 = blockIdx.y * 128, col0 = blockIdx.x * 128;                    \
  const int wm = (wave >> 1) * 64, wn = (wave & 1) * 64;                         \
  const floatx4 z = {0.f, 0.f, 0.f, 0.f};                                       \
  floatx4 acc[4][4];                                                             \
  _Pragma("unroll") for (int i = 0; i < 4; ++i)                                  \
  _Pragma("unroll") for (int j = 0; j < 4; ++j) acc[i][j] = z;                   \
  const int ar0 = tid >> 2, ac0 = (tid & 3) << 3;                                \
  unsigned short* lA0 = &As[wave * 512];                                         \
  unsigned short* lA1 = &As[2048 + wave * 512];                                  \
  unsigned short* lB0 = &Bs[wave * 512];                                         \
  unsigned short* lB1 = &Bs[2048 + wave * 512];                                  \
  const unsigned short* gA0 = (Aptr) + (size_t)(row0 + ar0) * (LDA) + (KOFF) + ac0;      \
  const unsigned short* gA1 = (Aptr) + (size_t)(row0 + 64 + ar0) * (LDA) + (KOFF) + ac0; \
  const unsigned short* gB0 = (Wptr) + (size_t)(col0 + ar0) * (LDB) + (KOFF) + ac0;      \
  const unsigned short* gB1 = (Wptr) + (size_t)(col0 + 64 + ar0) * (LDB) + (KOFF) + ac0; \
  for (int k0 = 0; k0 < (KLEN); k0 += 32) {                                      \
    gload16(gA0 + k0, lA0);                                                      \
    gload16(gA1 + k0, lA1);                                                      \
    gload16(gB0 + k0, lB0);                                                      \
    gload16(gB1 + k0, lB1);                                                      \
    __syncthreads();                                                             \
    bf16x8 af[4], bfr[4];                                                        \
    _Pragma("unroll") for (int i = 0; i < 4; ++i) {                              \
      af[i]  = *(const bf16x8*)&As[(wm + i * 16 + l16) * 32 + quad * 8];         \
      bfr[i] = *(const bf16x8*)&Bs[(wn + i * 16 + l16) * 32 + quad * 8];         \
    }                                                                            \
    _Pragma("unroll") for (int mi = 0; mi < 4; ++mi)                             \
    _Pragma("unroll") for (int ni = 0; ni < 4; ++ni)                             \
      acc[mi][ni] =                                                              \
          __builtin_amdgcn_mfma_f32_16x16x32_bf16(af[mi], bfr[ni], acc[mi][ni], 0, 0, 0); \
    __syncthreads();                                                             \
  }

// C[M,N] = A[M,K] * W[N,K]^T, all bf16
__global__ __launch_bounds__(256) void gemm_bt(
    const unsigned short* __restrict__ A, const unsigned short* __restrict__ W,
    unsigned short* __restrict__ C, int N, int K) {
  GEMM_CORE_G(A, W, K, K, K, 0)
#pragma unroll
  for (int mi = 0; mi < 4; ++mi) {
    const int r = row0 + wm + mi * 16 + quad * 4;
#pragma unroll
    for (int ni = 0; ni < 4; ++ni) {
      const int cc = col0 + wn + ni * 16 + l16;
#pragma unroll
      for (int reg = 0; reg < 4; ++reg)
        C[(size_t)(r + reg) * N + cc] = f2bf(acc[mi][ni][reg]);
    }
  }
}

// o-proj + residual: out (f32) = x (f32) + A*W^T   (h lives in d_out)
__global__ __launch_bounds__(256) void gemm_o_res(
    const unsigned short* __restrict__ A, const unsigned short* __restrict__ W,
    const float* __restrict__ X, float* __restrict__ Hout) {
  GEMM_CORE_G(A, W, DMODEL, DMODEL, DMODEL, 0)
#pragma unroll
  for (int mi = 0; mi < 4; ++mi) {
    const int r = row0 + wm + mi * 16 + quad * 4;
#pragma unroll
    for (int ni = 0; ni < 4; ++ni) {
      const int cc = col0 + wn + ni * 16 + l16;
#pragma unroll
      for (int reg = 0; reg < 4; ++reg) {
        const size_t idx = (size_t)(r + reg) * DMODEL + cc;
        Hout[idx] = X[idx] + acc[mi][ni][reg];
      }
    }
  }
}

// down-proj on COMPACTED rows, split-K over blockIdx.z, MoD scatter atomicAdd:
// out[tok] += scv * partial. (p0+p1)*scv distributes across K-splits and FF halves.
__global__ __launch_bounds__(256) void gemm_down_add(
    const unsigned short* __restrict__ A, const unsigned short* __restrict__ W,
    const float* __restrict__ ts, const int* __restrict__ tok_of,
    const int* __restrict__ cnt, float* __restrict__ out) {
  const int nrow = *cnt;
  if (blockIdx.y * 128 >= nrow) return;
  const int koff = blockIdx.z * (FFH / 2);
  GEMM_CORE_G(A, W, FFH, FFH, FFH / 2, koff)
#pragma unroll
  for (int mi = 0; mi < 4; ++mi) {
    const int r = row0 + wm + mi * 16 + quad * 4;
#pragma unroll
    for (int ni = 0; ni < 4; ++ni) {
      const int cc = col0 + wn + ni * 16 + l16;
#pragma unroll
      for (int reg = 0; reg < 4; ++reg) {
        const int rr = r + reg;
        if (rr < nrow) {
          const int tok = tok_of[rr];
          const float scv = 0.5f + (ts[tok] - 0.5f) * 0.7f;
          atomicAdd(out + (size_t)tok * DMODEL + cc, acc[mi][ni][reg] * scv);
        }
      }
    }
  }
}

// fused gate+up GEMM on COMPACTED rows with silu(g)*u epilogue. 128 rows x 64 cols.
__global__ __launch_bounds__(256) void gemm_gateup(
    const unsigned short* __restrict__ A, const unsigned short* __restrict__ G,
    const unsigned short* __restrict__ U, const int* __restrict__ cnt,
    unsigned short* __restrict__ act) {
  if (blockIdx.y * 128 >= *cnt) return;
  __shared__ __align__(16) unsigned short As[128 * 32];
  __shared__ __align__(16) unsigned short Gs[64 * 32];
  __shared__ __align__(16) unsigned short Us[64 * 32];
  const int tid  = threadIdx.x;
  const int wave = tid >> 6, lane = tid & 63;
  const int quad = lane >> 4, l16 = lane & 15;
  const int row0 = blockIdx.y * 128, colg = blockIdx.x * 64;
  const int wm = (wave >> 1) * 64, wn = (wave & 1) * 32;

  const floatx4 z = {0.f, 0.f, 0.f, 0.f};
  floatx4 accG[4][2], accU[4][2];
#pragma unroll
  for (int i = 0; i < 4; ++i)
#pragma unroll
    for (int j = 0; j < 2; ++j) { accG[i][j] = z; accU[i][j] = z; }

  const int ar0 = tid >> 2, ac0 = (tid & 3) << 3;
  unsigned short* lA0 = &As[wave * 512];
  unsigned short* lA1 = &As[2048 + wave * 512];
  unsigned short* lG  = &Gs[wave * 512];
  unsigned short* lU  = &Us[wave * 512];
  const unsigned short* gA0 = A + (size_t)(row0 + ar0) * DMODEL + ac0;
  const unsigned short* gA1 = A + (size_t)(row0 + 64 + ar0) * DMODEL + ac0;
  const unsigned short* gG  = G + (size_t)(colg + ar0) * DMODEL + ac0;
  const unsigned short* gU  = U + (size_t)(colg + ar0) * DMODEL + ac0;

  for (int k0 = 0; k0 < DMODEL; k0 += 32) {
    gload16(gA0 + k0, lA0);
    gload16(gA1 + k0, lA1);
    gload16(gG + k0, lG);
    gload16(gU + k0, lU);
    __syncthreads();
    bf16x8 af[4], bg[2], bu[2];
#pragma unroll
    for (int i = 0; i < 4; ++i)
      af[i] = *(const bf16x8*)&As[(wm + i * 16 + l16) * 32 + quad * 8];
#pragma unroll
    for (int j = 0; j < 2; ++j) {
      bg[j] = *(const bf16x8*)&Gs[(wn + j * 16 + l16) * 32 + quad * 8];
      bu[j] = *(const bf16x8*)&Us[(wn + j * 16 + l16) * 32 + quad * 8];
    }
#pragma unroll
    for (int mi = 0; mi < 4; ++mi)
#pragma unroll
      for (int ni = 0; ni < 2; ++ni) {
        accG[mi][ni] = __builtin_amdgcn_mfma_f32_16x16x32_bf16(af[mi], bg[ni], accG[mi][ni], 0, 0, 0);
        accU[mi][ni] = __builtin_amdgcn_mfma_f32_16x16x32_bf16(af[mi], bu[ni], accU[mi][ni], 0, 0, 0);
      }
    __syncthreads();
  }
#pragma unroll
  for (int mi = 0; mi < 4; ++mi) {
    const int r = row0 + wm + mi * 16 + quad * 4;
#pragma unroll
    for (int ni = 0; ni < 2; ++ni) {
      const int cc = colg + wn + ni * 16 + l16;
#pragma unroll
      for (int reg = 0; reg < 4; ++reg) {
        const float g = accG[mi][ni][reg];
        const float u = accU[mi][ni][reg];
        const float s = g / (1.f + __expf(-g));
        act[(size_t)(r + reg) * FFH + cc] = f2bf(s * u);
      }
    }
  }
}

// ---------------- RMSNorm (ln1): f32 in, f32 weight, bf16 out --------------------
__global__ __launch_bounds__(256) void rmsnorm_f32(
    const float* __restrict__ x, const float* __restrict__ w,
    unsigned short* __restrict__ out) {
  __shared__ float red[4];
  const int row = blockIdx.x, tid = threadIdx.x;
  const int lane = tid & 63, wave = tid >> 6;
  const size_t base = (size_t)row * DMODEL + tid * 8;
  float4 a = *(const float4*)(x + base);
  float4 b = *(const float4*)(x + base + 4);
  float v[8] = {a.x, a.y, a.z, a.w, b.x, b.y, b.z, b.w};
  float ss = 0.f;
#pragma unroll
  for (int j = 0; j < 8; ++j) ss += v[j] * v[j];
#pragma unroll
  for (int off = 32; off; off >>= 1) ss += __shfl_xor(ss, off);
  if (lane == 0) red[wave] = ss;
  __syncthreads();
  const float tot = red[0] + red[1] + red[2] + red[3];
  const float rms = rsqrtf(tot * (1.f / (float)DMODEL) + 1e-5f);
  float4 wa = *(const float4*)(w + tid * 8);
  float4 wb = *(const float4*)(w + tid * 8 + 4);
  const float wv[8] = {wa.x, wa.y, wa.z, wa.w, wb.x, wb.y, wb.z, wb.w};
  unsigned short o[8];
#pragma unroll
  for (int j = 0; j < 8; ++j) o[j] = f2bf(v[j] * rms * wv[j]);
  *(uint4*)(out + base) = *(const uint4*)o;
}

// ---------------- RMSNorm (ln2) + MoD compaction gather --------------------------
__global__ __launch_bounds__(256) void rms_gather(
    const float* __restrict__ x, const float* __restrict__ w,
    const int* __restrict__ mask, int* __restrict__ cnt,
    int* __restrict__ tok_of, unsigned short* __restrict__ xc) {
  const int row = blockIdx.x;
  if (!mask[row]) return;
  __shared__ float red[4];
  __shared__ int ppos;
  const int tid = threadIdx.x, lane = tid & 63, wave = tid >> 6;
  if (tid == 0) { const int p = atomicAdd(cnt, 1); ppos = p; tok_of[p] = row; }
  const size_t base = (size_t)row * DMODEL + tid * 8;
  float4 a = *(const float4*)(x + base);
  float4 b = *(const float4*)(x + base + 4);
  float v[8] = {a.x, a.y, a.z, a.w, b.x, b.y, b.z, b.w};
  float ss = 0.f;
#pragma unroll
  for (int j = 0; j < 8; ++j) ss += v[j] * v[j];
#pragma unroll
  for (int off = 32; off; off >>= 1) ss += __shfl_xor(ss, off);
  if (lane == 0) red[wave] = ss;
  __syncthreads();  // covers red[] and ppos
  const float tot = red[0] + red[1] + red[2] + red[3];
  const float rms = rsqrtf(tot * (1.f / (float)DMODEL) + 1e-5f);
  float4 wa = *(const float4*)(w + tid * 8);
  float4 wb = *(const float4*)(w + tid * 8 + 4);
  const float wv[8] = {wa.x, wa.y, wa.z, wa.w, wb.x, wb.y, wb.z, wb.w};
  unsigned short o[8];
#pragma unroll
  for (int j = 0; j < 8; ++j) o[j] = f2bf(v[j] * rms * wv[j]);
  *(uint4*)(xc + (size_t)ppos * DMODEL + tid * 8) = *(const uint4*)o;
}

// ---------------- RoPE in-place, row stride rstride (bf16) ----------------------
__global__ __launch_bounds__(256) void rope_k(unsigned short* __restrict__ buf,
                                              int nh, int rstride) {
  const int t = blockIdx.x;
  const int s = t & (SEQ - 1);
  const int d = threadIdx.x & 63;
  const float inv = __expf((float)d * -0.14391156843712787f);
  float sn, cs;
  __sincosf((float)s * inv, &sn, &cs);
  const int npair = nh * 64;
  for (int idx = threadIdx.x; idx < npair; idx += 256) {
    const int hh = idx >> 6;
    unsigned short* p = buf + (size_t)t * rstride + hh * 128 + d;
    const float x1 = bf2f(p[0]), x2 = bf2f(p[64]);
    p[0]  = f2bf(x1 * cs - x2 * sn);
    p[64] = f2bf(x2 * cs + x1 * sn);
  }
}

// ---------------- Flash attention, causal, GQA rep=4 (bf16 in/out) --------------
// 64-row causal pairing: block = (h, pair y, b) handles q-tiles qtH=31-y and qtL=y
// (64 rows each, 4 waves x 16 rows). Work = 33 tile-units/block, grid 512 = 2/CU
// (LDS 48KB -> 3 blocks/CU capacity). K/V staged once per tile, shared by both
// contexts. Vt XOR-swizzled; register prefetch (T14); defer-max (T13); setprio.
__global__ __launch_bounds__(256, 2) void attn(
    const unsigned short* __restrict__ QKV,
    unsigned short* __restrict__ O) {
  __shared__ __align__(16) unsigned short Ks[64 * 136];
  __shared__ __align__(16) unsigned short Vt[128 * 80];
  __shared__ __align__(16) unsigned short Ps[4][16 * 88];
  const int h = blockIdx.x, b = blockIdx.z;
  const int qtL = blockIdx.y, qtH = 31 - qtL;
  const int kvh = h >> 2;
  const int tid = threadIdx.x, wave = tid >> 6, lane = tid & 63;
  const int quad = lane >> 4, l16 = lane & 15;
  const int wloH = qtH * 64 + wave * 16;
  const int wloL = qtL * 64 + wave * 16;
  const int qrH = wloH + quad * 4, qrL = wloL + quad * 4;
  const float sscale = 0.08838834764831845f;  // 1/sqrt(128)

  bf16x8 qfH[4], qfL[4];
  {
    const unsigned short* qpH =
        QKV + (size_t)(b * SEQ + wloH + l16) * QKVS + h * HDIM + quad * 8;
    const unsigned short* qpL =
        QKV + (size_t)(b * SEQ + wloL + l16) * QKVS + h * HDIM + quad * 8;
#pragma unroll
    for (int c = 0; c < 4; ++c) {
      qfH[c] = *(const bf16x8*)(qpH + 32 * c);
      qfL[c] = *(const bf16x8*)(qpL + 32 * c);
    }
  }
  const floatx4 z = {0.f, 0.f, 0.f, 0.f};
  floatx4 accH[8], accL[8];
#pragma unroll
  for (int i = 0; i < 8; ++i) { accH[i] = z; accL[i] = z; }
  float mH[4], lH[4], mL[4], lL[4];
#pragma unroll
  for (int r = 0; r < 4; ++r) { mH[r] = -1e30f; lH[r] = 0.f; mL[r] = -1e30f; lL[r] = 0.f; }

  // staging coords over 256 threads: token row sr+16*it, dim cols scol..scol+7
  const int sr = tid >> 4, scol = (tid & 15) * 8;
  const unsigned short* kvb = QKV + (size_t)(b * SEQ) * QKVS + kvh * HDIM;
  uint4 kreg[4], vreg[4];

  auto LOADT = [&](int t0) {
#pragma unroll
    for (int it = 0; it < 4; ++it) {
      const int r = sr + it * 16;
      kreg[it] = *(const uint4*)(kvb + (size_t)(t0 + r) * QKVS + 2048 + scol);
      vreg[it] = *(const uint4*)(kvb + (size_t)(t0 + r) * QKVS + 2560 + scol);
    }
  };
  auto STORET = [&]() {
#pragma unroll
    for (int it = 0; it < 4; ++it) {
      const int r = sr + it * 16;
      *(uint4*)&Ks[r * 136 + scol] = kreg[it];
      const unsigned short* dv = (const unsigned short*)&vreg[it];
      const int tb = r >> 3, pos = r & 7;
#pragma unroll
      for (int j = 0; j < 8; ++j) {
        const int d = scol + j;
        const int sb = tb ^ ((d >> 3) & 7);
        Vt[d * 80 + sb * 8 + pos] = dv[j];
      }
    }
  };

  // one q-context compute step against the staged 64-token tile
  auto COMPUTE = [&](const bf16x8* qf, floatx4* accO, float* mrow, float* lrow,
                     int qrowC, int wlo, int t0) {
    floatx4 sc[4];
    __builtin_amdgcn_s_setprio(1);
#pragma unroll
    for (int ni = 0; ni < 4; ++ni) {
      floatx4 s = z;
#pragma unroll
      for (int c = 0; c < 4; ++c) {
        bf16x8 kf = *(const bf16x8*)&Ks[(ni * 16 + l16) * 136 + c * 32 + quad * 8];
        s = __builtin_amdgcn_mfma_f32_16x16x32_bf16(qf[c], kf, s, 0, 0, 0);
      }
      sc[ni] = s;
    }
    __builtin_amdgcn_s_setprio(0);

    if (t0 + 63 > wlo) {  // diagonal tile for this wave: causal mask
#pragma unroll
      for (int ni = 0; ni < 4; ++ni) {
        const int kcol = t0 + ni * 16 + l16;
#pragma unroll
        for (int reg = 0; reg < 4; ++reg) {
          const float vv = sc[ni][reg] * sscale;
          sc[ni][reg] = (kcol > qrowC + reg) ? -1e30f : vv;
        }
      }
    } else {
#pragma unroll
      for (int ni = 0; ni < 4; ++ni)
#pragma unroll
        for (int reg = 0; reg < 4; ++reg) sc[ni][reg] *= sscale;
    }

    float mx[4];
#pragma unroll
    for (int reg = 0; reg < 4; ++reg) {
      float m0 = fmaxf(fmaxf(sc[0][reg], sc[1][reg]), fmaxf(sc[2][reg], sc[3][reg]));
#pragma unroll
      for (int off = 1; off < 16; off <<= 1) m0 = fmaxf(m0, __shfl_xor(m0, off));
      mx[reg] = m0;
    }
    const bool grow = (mx[0] > mrow[0] + 8.f) || (mx[1] > mrow[1] + 8.f) ||
                      (mx[2] > mrow[2] + 8.f) || (mx[3] > mrow[3] + 8.f);
    if (__any(grow)) {
#pragma unroll
      for (int reg = 0; reg < 4; ++reg) {
        const float mnew = fmaxf(mrow[reg], mx[reg]);
        const float alpha = __expf(mrow[reg] - mnew);
        mrow[reg] = mnew;
        lrow[reg] *= alpha;
#pragma unroll
        for (int nd = 0; nd < 8; ++nd) accO[nd][reg] *= alpha;
      }
    }
#pragma unroll
    for (int reg = 0; reg < 4; ++reg) {
      float rs = 0.f;
#pragma unroll
      for (int ni = 0; ni < 4; ++ni) {
        const float p = __expf(sc[ni][reg] - mrow[reg]);
        sc[ni][reg] = p;
        rs += p;
      }
#pragma unroll
      for (int off = 1; off < 16; off <<= 1) rs += __shfl_xor(rs, off);
      lrow[reg] += rs;
    }
    // Ps is per-wave: lgkmcnt orders write->read, no barrier needed
#pragma unroll
    for (int ni = 0; ni < 4; ++ni)
#pragma unroll
      for (int reg = 0; reg < 4; ++reg)
        Ps[wave][(quad * 4 + reg) * 88 + ni * 16 + l16] = f2bf(sc[ni][reg]);
    const bf16x8 pa0 = *(const bf16x8*)&Ps[wave][l16 * 88 + quad * 8];
    const bf16x8 pa1 = *(const bf16x8*)&Ps[wave][l16 * 88 + 32 + quad * 8];
    __builtin_amdgcn_s_setprio(1);
#pragma unroll
    for (int nd = 0; nd < 8; ++nd) {
      const int d = nd * 16 + l16;
      const int f = (d >> 3) & 7;
      bf16x8 v0 = *(const bf16x8*)&Vt[d * 80 + ((quad ^ f) << 3)];
      bf16x8 v1 = *(const bf16x8*)&Vt[d * 80 + (((quad + 4) ^ f) << 3)];
      accO[nd] = __builtin_amdgcn_mfma_f32_16x16x32_bf16(pa0, v0, accO[nd], 0, 0, 0);
      accO[nd] = __builtin_amdgcn_mfma_f32_16x16x32_bf16(pa1, v1, accO[nd], 0, 0, 0);
    }
    __builtin_amdgcn_s_setprio(0);
  };

  const int ntL = qtL + 1, ntH = qtH + 1;
  LOADT(0);
  STORET();
  __syncthreads();

  for (int ti = 0; ti < ntH; ++ti) {
    const int t0 = ti * 64;
    const bool more = (ti + 1 < ntH);
    if (more) LOADT(t0 + 64);  // prefetch hides under compute

    COMPUTE(qfH, accH, mH, lH, qrH, wloH, t0);
    if (ti < ntL) COMPUTE(qfL, accL, mL, lL, qrL, wloL, t0);

    __syncthreads();            // all waves done reading Ks/Vt
    if (more) {
      STORET();                 // write prefetched tile
      __syncthreads();
    }
  }
#pragma unroll
  for (int nd = 0; nd < 8; ++nd)
#pragma unroll
    for (int reg = 0; reg < 4; ++reg) {
      const float oH = accH[nd][reg] / lH[reg];
      O[(size_t)(b * SEQ + qrH + reg) * (NHEAD * HDIM) + h * HDIM + nd * 16 + l16] = f2bf(oH);
      const float oL = accL[nd][reg] / lL[reg];
      O[(size_t)(b * SEQ + qrL + reg) * (NHEAD * HDIM) + h * HDIM + nd * 16 + l16] = f2bf(oL);
    }
}

// ---------------- launch --------------------------------------------------------
extern "C" void kernel_launch(void* const* d_in, const int* in_sizes, int n_in,
                              void* d_out, int out_size, void* d_ws, size_t ws_size,
                              hipStream_t stream) {
  (void)in_sizes; (void)n_in; (void)out_size; (void)ws_size;
  const float* x    = (const float*)d_in[0];
  const int*   mask = (const int*)d_in[1];
  const float* ts   = (const float*)d_in[2];
  const float* ln1  = (const float*)d_in[3];
  const float* ln2  = (const float*)d_in[4];
  const float* q_w  = (const float*)d_in[5];
  const float* k_w  = (const float*)d_in[6];
  const float* v_w  = (const float*)d_in[7];
  const float* o_w  = (const float*)d_in[8];
  const float* g_w  = (const float*)d_in[9];
  const float* u_w  = (const float*)d_in[10];
  const float* dn_w = (const float*)d_in[11];
  float* out = (float*)d_out;

  // workspace layout (h residual lives in d_out):
  // attn phase: xn [0,16.78M) | qkv [16.78,41.94) | wqkv/attno [41.94,58.72) | wo [58.72,67.11)
  // MLP phase:  xc [0,16.78M) | wg|wu [16.78,46.14) | wdn [16.78,31.46) | act [46.14,75.50)
  // meta: cnt @75.50M, tok_of @75.50M+4K
  char* ws = (char*)d_ws;
  unsigned short* xn    = (unsigned short*)(ws + 0);
  unsigned short* qkv   = (unsigned short*)(ws + 16777216);
  unsigned short* wqkv  = (unsigned short*)(ws + 41943040);
  unsigned short* attno = (unsigned short*)(ws + 41943040);  // overlays wqkv (dead)
  unsigned short* wo    = (unsigned short*)(ws + 58720256);
  unsigned short* xc    = (unsigned short*)(ws + 0);         // compacted ln2-norm rows
  unsigned short* wg    = (unsigned short*)(ws + 16777216);  // wu contiguous after wg
  unsigned short* wu    = (unsigned short*)(ws + 31457280);
  unsigned short* wdn   = (unsigned short*)(ws + 16777216);  // overlays wg (dead)
  unsigned short* act   = (unsigned short*)(ws + 46137344);  // [<=NTOK][FFH]
  int*            cnt   = (int*)           (ws + 75497472);
  int*            tok_of= (int*)           (ws + 75501568);

  // --- attention block ---
  wconv_attn<<<5120, 256, 0, stream>>>(q_w, k_w, v_w, o_w, wqkv, wo, cnt);
  rmsnorm_f32<<<NTOK, 256, 0, stream>>>(x, ln1, xn);
  gemm_bt<<<dim3(QKVS / 128, 32), 256, 0, stream>>>(xn, wqkv, qkv, QKVS, 2048);  // fused q+k+v
  rope_k<<<NTOK, 256, 0, stream>>>(qkv, 20, QKVS);  // q heads 0..15, k heads 16..19
  attn<<<dim3(NHEAD, 16, 2), 256, 0, stream>>>(qkv, attno);
  gemm_o_res<<<dim3(16, 32), 256, 0, stream>>>(attno, wo, x, out);  // out := h

  // --- MoD MLP on compacted tokens, two FF halves, scatter-add into out ---
  rms_gather<<<NTOK, 256, 0, stream>>>(out, ln2, mask, cnt, tok_of, xc);
  for (int hf = 0; hf < 2; ++hf) {
    wconv_gu<<<2 * FFH, 256, 0, stream>>>(g_w, u_w, wg, hf);  // 7168 blocks (one per row!)
    gemm_gateup<<<dim3(FFH / 64, 32), 256, 0, stream>>>(xc, wg, wu, cnt, act);
    wconv_dn<<<2048, 256, 0, stream>>>(dn_w, wdn, hf * FFH);
    gemm_down_add<<<dim3(16, 32, 2), 256, 0, stream>>>(act, wdn, ts, tok_of, cnt, out);
  }
}

// Round 7
// 906.881 us; speedup vs baseline: 1.1365x; 1.1365x over previous
//
#include <hip/hip_runtime.h>
#include <stdint.h>

#define SEQ    2048
#define DMODEL 2048
#define NTOK   4096   // B*S
#define NHEAD  16
#define NKVH   4
#define HDIM   128
#define FFDIM  7168
#define FFH    3584   // FFDIM / 2 (MLP processed in two column halves to fit workspace)
#define QKVS   3072   // merged qkv row stride: q[0,2048) k[2048,2560) v[2560,3072)

typedef __bf16 bf16x8 __attribute__((ext_vector_type(8)));
typedef float  floatx4 __attribute__((ext_vector_type(4)));

__device__ __forceinline__ float bf2f(unsigned short u) {
  union { unsigned int i; float f; } v; v.i = ((unsigned int)u) << 16; return v.f;
}
__device__ __forceinline__ unsigned short f2bf(float f) {
  union { float f; unsigned int u; } v; v.f = f;
  unsigned int r = (v.u + 0x7FFFu + ((v.u >> 16) & 1u)) >> 16;
  return (unsigned short)r;
}
// 8 f32 elements (32B) from f32 memory, converted to 8 bf16 (16B)
__device__ __forceinline__ uint4 ld8f32(const float* p) {
  float4 a = *(const float4*)p, b = *(const float4*)(p + 4);
  union { unsigned short s[8]; uint4 v; } o;
  o.s[0] = f2bf(a.x); o.s[1] = f2bf(a.y); o.s[2] = f2bf(a.z); o.s[3] = f2bf(a.w);
  o.s[4] = f2bf(b.x); o.s[5] = f2bf(b.y); o.s[6] = f2bf(b.z); o.s[7] = f2bf(b.w);
  return o.v;
}

// async HBM->LDS, 16B per lane. LDS dest = wave-uniform base + lane*16 (linear!).
__device__ __forceinline__ void gload16(const unsigned short* g, unsigned short* l) {
  __builtin_amdgcn_global_load_lds(
      (const __attribute__((address_space(1))) unsigned int*)g,
      (__attribute__((address_space(3))) unsigned int*)l, 16, 0, 0);
}

// ---------------- fused attn-weight conversion + MoD counter zero ----------------
// blocks 0..2047: q rows; 2048..2559: k; 2560..3071: v; 3072..5119: o.
__global__ __launch_bounds__(256) void wconv_attn(
    const float* __restrict__ q, const float* __restrict__ k,
    const float* __restrict__ v, const float* __restrict__ o,
    unsigned short* __restrict__ wqkv, unsigned short* __restrict__ wo,
    int* __restrict__ cnt) {
  if (blockIdx.x == 0 && threadIdx.x == 0) *cnt = 0;
  const int r = blockIdx.x;
  const float* src;
  unsigned short* dst;
  if (r < 2048)      { src = q + (size_t)r * DMODEL;          dst = wqkv + (size_t)r * DMODEL; }
  else if (r < 2560) { src = k + (size_t)(r - 2048) * DMODEL; dst = wqkv + (size_t)r * DMODEL; }
  else if (r < 3072) { src = v + (size_t)(r - 2560) * DMODEL; dst = wqkv + (size_t)r * DMODEL; }
  else               { src = o + (size_t)(r - 3072) * DMODEL; dst = wo + (size_t)(r - 3072) * DMODEL; }
  const int c = threadIdx.x * 8;
  *(uint4*)(dst + c) = ld8f32(src + c);
}

// ---------------- fused gate+up conversion (dst: wg|wu contiguous) ---------------
// grid MUST be 2*FFH = 7168 blocks (one per dst row).
__global__ __launch_bounds__(256) void wconv_gu(
    const float* __restrict__ g, const float* __restrict__ u,
    unsigned short* __restrict__ dst, int hf) {
  const int r = blockIdx.x;  // 0..7167
  const float* src = (r < FFH) ? g + ((size_t)hf * FFH + r) * DMODEL
                               : u + ((size_t)hf * FFH + (r - FFH)) * DMODEL;
  const int c = threadIdx.x * 8;
  *(uint4*)(dst + (size_t)r * DMODEL + c) = ld8f32(src + c);
}

// strided conversion for down-proj K-slice: src [DMODEL][FFDIM], cols [koff,koff+FFH)
__global__ __launch_bounds__(256) void wconv_dn(const float* __restrict__ s,
                                                unsigned short* __restrict__ d, int koff) {
  const int r = blockIdx.x;  // 2048 rows
  const float* sp = s + (size_t)r * FFDIM + koff;
  unsigned short* dp = d + (size_t)r * FFH;
  for (int c = threadIdx.x * 8; c < FFH; c += 2048)
    *(uint4*)(dp + c) = ld8f32(sp + c);
}

// ======== GEMM core: 128x128 tile, BK=32, 4 waves, A bf16 / W bf16 ==============
// LDA/LDB row strides, KLEN loop length, KOFF column offset (for split-K).
#define GEMM_CORE_G(Aptr, Wptr, LDA, LDB, KLEN, KOFF)                            \
  __shared__ __align__(16) unsigned short As[128 * 32];                          \
  __shared__ __align__(16) unsigned short Bs[128 * 32];                          \
  const int tid  = threadIdx.x;                                                  \
  const int wave = tid >> 6, lane = tid & 63;                                    \
  const int quad = lane >> 4, l16 = lane & 15;                                   \
  const int row0 = blockIdx.y * 128, col0 = blockIdx.x * 128;                    \
  const int wm = (wave >> 1) * 64, wn = (wave & 1) * 64;                         \
  const floatx4 z = {0.f, 0.f, 0.f, 0.f};                                       \
  floatx4 acc[4][4];                                                             \
  _Pragma("unroll") for (int i = 0; i < 4; ++i)                                  \
  _Pragma("unroll") for (int j = 0; j < 4; ++j) acc[i][j] = z;                   \
  const int ar0 = tid >> 2, ac0 = (tid & 3) << 3;                                \
  unsigned short* lA0 = &As[wave * 512];                                         \
  unsigned short* lA1 = &As[2048 + wave * 512];                                  \
  unsigned short* lB0 = &Bs[wave * 512];                                         \
  unsigned short* lB1 = &Bs[2048 + wave * 512];                                  \
  const unsigned short* gA0 = (Aptr) + (size_t)(row0 + ar0) * (LDA) + (KOFF) + ac0;      \
  const unsigned short* gA1 = (Aptr) + (size_t)(row0 + 64 + ar0) * (LDA) + (KOFF) + ac0; \
  const unsigned short* gB0 = (Wptr) + (size_t)(col0 + ar0) * (LDB) + (KOFF) + ac0;      \
  const unsigned short* gB1 = (Wptr) + (size_t)(col0 + 64 + ar0) * (LDB) + (KOFF) + ac0; \
  for (int k0 = 0; k0 < (KLEN); k0 += 32) {                                      \
    gload16(gA0 + k0, lA0);                                                      \
    gload16(gA1 + k0, lA1);                                                      \
    gload16(gB0 + k0, lB0);                                                      \
    gload16(gB1 + k0, lB1);                                                      \
    __syncthreads();                                                             \
    bf16x8 af[4], bfr[4];                                                        \
    _Pragma("unroll") for (int i = 0; i < 4; ++i) {                              \
      af[i]  = *(const bf16x8*)&As[(wm + i * 16 + l16) * 32 + quad * 8];         \
      bfr[i] = *(const bf16x8*)&Bs[(wn + i * 16 + l16) * 32 + quad * 8];         \
    }                                                                            \
    _Pragma("unroll") for (int mi = 0; mi < 4; ++mi)                             \
    _Pragma("unroll") for (int ni = 0; ni < 4; ++ni)                             \
      acc[mi][ni] =                                                              \
          __builtin_amdgcn_mfma_f32_16x16x32_bf16(af[mi], bfr[ni], acc[mi][ni], 0, 0, 0); \
    __syncthreads();                                                             \
  }

// C[M,N] = A[M,K] * W[N,K]^T, all bf16
__global__ __launch_bounds__(256) void gemm_bt(
    const unsigned short* __restrict__ A, const unsigned short* __restrict__ W,
    unsigned short* __restrict__ C, int N, int K) {
  GEMM_CORE_G(A, W, K, K, K, 0)
#pragma unroll
  for (int mi = 0; mi < 4; ++mi) {
    const int r = row0 + wm + mi * 16 + quad * 4;
#pragma unroll
    for (int ni = 0; ni < 4; ++ni) {
      const int cc = col0 + wn + ni * 16 + l16;
#pragma unroll
      for (int reg = 0; reg < 4; ++reg)
        C[(size_t)(r + reg) * N + cc] = f2bf(acc[mi][ni][reg]);
    }
  }
}

// o-proj + residual: out (f32) = x (f32) + A*W^T   (h lives in d_out)
__global__ __launch_bounds__(256) void gemm_o_res(
    const unsigned short* __restrict__ A, const unsigned short* __restrict__ W,
    const float* __restrict__ X, float* __restrict__ Hout) {
  GEMM_CORE_G(A, W, DMODEL, DMODEL, DMODEL, 0)
#pragma unroll
  for (int mi = 0; mi < 4; ++mi) {
    const int r = row0 + wm + mi * 16 + quad * 4;
#pragma unroll
    for (int ni = 0; ni < 4; ++ni) {
      const int cc = col0 + wn + ni * 16 + l16;
#pragma unroll
      for (int reg = 0; reg < 4; ++reg) {
        const size_t idx = (size_t)(r + reg) * DMODEL + cc;
        Hout[idx] = X[idx] + acc[mi][ni][reg];
      }
    }
  }
}

// down-proj on COMPACTED rows, split-K over blockIdx.z, MoD scatter atomicAdd:
// out[tok] += scv * partial. (p0+p1)*scv distributes across K-splits and FF halves.
__global__ __launch_bounds__(256) void gemm_down_add(
    const unsigned short* __restrict__ A, const unsigned short* __restrict__ W,
    const float* __restrict__ ts, const int* __restrict__ tok_of,
    const int* __restrict__ cnt, float* __restrict__ out) {
  const int nrow = *cnt;
  if (blockIdx.y * 128 >= nrow) return;
  const int koff = blockIdx.z * (FFH / 2);
  GEMM_CORE_G(A, W, FFH, FFH, FFH / 2, koff)
#pragma unroll
  for (int mi = 0; mi < 4; ++mi) {
    const int r = row0 + wm + mi * 16 + quad * 4;
#pragma unroll
    for (int ni = 0; ni < 4; ++ni) {
      const int cc = col0 + wn + ni * 16 + l16;
#pragma unroll
      for (int reg = 0; reg < 4; ++reg) {
        const int rr = r + reg;
        if (rr < nrow) {
          const int tok = tok_of[rr];
          const float scv = 0.5f + (ts[tok] - 0.5f) * 0.7f;
          atomicAdd(out + (size_t)tok * DMODEL + cc, acc[mi][ni][reg] * scv);
        }
      }
    }
  }
}

// fused gate+up GEMM on COMPACTED rows with silu(g)*u epilogue. 128 rows x 64 cols.
__global__ __launch_bounds__(256) void gemm_gateup(
    const unsigned short* __restrict__ A, const unsigned short* __restrict__ G,
    const unsigned short* __restrict__ U, const int* __restrict__ cnt,
    unsigned short* __restrict__ act) {
  if (blockIdx.y * 128 >= *cnt) return;
  __shared__ __align__(16) unsigned short As[128 * 32];
  __shared__ __align__(16) unsigned short Gs[64 * 32];
  __shared__ __align__(16) unsigned short Us[64 * 32];
  const int tid  = threadIdx.x;
  const int wave = tid >> 6, lane = tid & 63;
  const int quad = lane >> 4, l16 = lane & 15;
  const int row0 = blockIdx.y * 128, colg = blockIdx.x * 64;
  const int wm = (wave >> 1) * 64, wn = (wave & 1) * 32;

  const floatx4 z = {0.f, 0.f, 0.f, 0.f};
  floatx4 accG[4][2], accU[4][2];
#pragma unroll
  for (int i = 0; i < 4; ++i)
#pragma unroll
    for (int j = 0; j < 2; ++j) { accG[i][j] = z; accU[i][j] = z; }

  const int ar0 = tid >> 2, ac0 = (tid & 3) << 3;
  unsigned short* lA0 = &As[wave * 512];
  unsigned short* lA1 = &As[2048 + wave * 512];
  unsigned short* lG  = &Gs[wave * 512];
  unsigned short* lU  = &Us[wave * 512];
  const unsigned short* gA0 = A + (size_t)(row0 + ar0) * DMODEL + ac0;
  const unsigned short* gA1 = A + (size_t)(row0 + 64 + ar0) * DMODEL + ac0;
  const unsigned short* gG  = G + (size_t)(colg + ar0) * DMODEL + ac0;
  const unsigned short* gU  = U + (size_t)(colg + ar0) * DMODEL + ac0;

  for (int k0 = 0; k0 < DMODEL; k0 += 32) {
    gload16(gA0 + k0, lA0);
    gload16(gA1 + k0, lA1);
    gload16(gG + k0, lG);
    gload16(gU + k0, lU);
    __syncthreads();
    bf16x8 af[4], bg[2], bu[2];
#pragma unroll
    for (int i = 0; i < 4; ++i)
      af[i] = *(const bf16x8*)&As[(wm + i * 16 + l16) * 32 + quad * 8];
#pragma unroll
    for (int j = 0; j < 2; ++j) {
      bg[j] = *(const bf16x8*)&Gs[(wn + j * 16 + l16) * 32 + quad * 8];
      bu[j] = *(const bf16x8*)&Us[(wn + j * 16 + l16) * 32 + quad * 8];
    }
#pragma unroll
    for (int mi = 0; mi < 4; ++mi)
#pragma unroll
      for (int ni = 0; ni < 2; ++ni) {
        accG[mi][ni] = __builtin_amdgcn_mfma_f32_16x16x32_bf16(af[mi], bg[ni], accG[mi][ni], 0, 0, 0);
        accU[mi][ni] = __builtin_amdgcn_mfma_f32_16x16x32_bf16(af[mi], bu[ni], accU[mi][ni], 0, 0, 0);
      }
    __syncthreads();
  }
#pragma unroll
  for (int mi = 0; mi < 4; ++mi) {
    const int r = row0 + wm + mi * 16 + quad * 4;
#pragma unroll
    for (int ni = 0; ni < 2; ++ni) {
      const int cc = colg + wn + ni * 16 + l16;
#pragma unroll
      for (int reg = 0; reg < 4; ++reg) {
        const float g = accG[mi][ni][reg];
        const float u = accU[mi][ni][reg];
        const float s = g / (1.f + __expf(-g));
        act[(size_t)(r + reg) * FFH + cc] = f2bf(s * u);
      }
    }
  }
}

// ---------------- RMSNorm (ln1): f32 in, f32 weight, bf16 out --------------------
__global__ __launch_bounds__(256) void rmsnorm_f32(
    const float* __restrict__ x, const float* __restrict__ w,
    unsigned short* __restrict__ out) {
  __shared__ float red[4];
  const int row = blockIdx.x, tid = threadIdx.x;
  const int lane = tid & 63, wave = tid >> 6;
  const size_t base = (size_t)row * DMODEL + tid * 8;
  float4 a = *(const float4*)(x + base);
  float4 b = *(const float4*)(x + base + 4);
  float v[8] = {a.x, a.y, a.z, a.w, b.x, b.y, b.z, b.w};
  float ss = 0.f;
#pragma unroll
  for (int j = 0; j < 8; ++j) ss += v[j] * v[j];
#pragma unroll
  for (int off = 32; off; off >>= 1) ss += __shfl_xor(ss, off);
  if (lane == 0) red[wave] = ss;
  __syncthreads();
  const float tot = red[0] + red[1] + red[2] + red[3];
  const float rms = rsqrtf(tot * (1.f / (float)DMODEL) + 1e-5f);
  float4 wa = *(const float4*)(w + tid * 8);
  float4 wb = *(const float4*)(w + tid * 8 + 4);
  const float wv[8] = {wa.x, wa.y, wa.z, wa.w, wb.x, wb.y, wb.z, wb.w};
  unsigned short o[8];
#pragma unroll
  for (int j = 0; j < 8; ++j) o[j] = f2bf(v[j] * rms * wv[j]);
  *(uint4*)(out + base) = *(const uint4*)o;
}

// ---------------- RMSNorm (ln2) + MoD compaction gather --------------------------
__global__ __launch_bounds__(256) void rms_gather(
    const float* __restrict__ x, const float* __restrict__ w,
    const int* __restrict__ mask, int* __restrict__ cnt,
    int* __restrict__ tok_of, unsigned short* __restrict__ xc) {
  const int row = blockIdx.x;
  if (!mask[row]) return;
  __shared__ float red[4];
  __shared__ int ppos;
  const int tid = threadIdx.x, lane = tid & 63, wave = tid >> 6;
  if (tid == 0) { const int p = atomicAdd(cnt, 1); ppos = p; tok_of[p] = row; }
  const size_t base = (size_t)row * DMODEL + tid * 8;
  float4 a = *(const float4*)(x + base);
  float4 b = *(const float4*)(x + base + 4);
  float v[8] = {a.x, a.y, a.z, a.w, b.x, b.y, b.z, b.w};
  float ss = 0.f;
#pragma unroll
  for (int j = 0; j < 8; ++j) ss += v[j] * v[j];
#pragma unroll
  for (int off = 32; off; off >>= 1) ss += __shfl_xor(ss, off);
  if (lane == 0) red[wave] = ss;
  __syncthreads();  // covers red[] and ppos
  const float tot = red[0] + red[1] + red[2] + red[3];
  const float rms = rsqrtf(tot * (1.f / (float)DMODEL) + 1e-5f);
  float4 wa = *(const float4*)(w + tid * 8);
  float4 wb = *(const float4*)(w + tid * 8 + 4);
  const float wv[8] = {wa.x, wa.y, wa.z, wa.w, wb.x, wb.y, wb.z, wb.w};
  unsigned short o[8];
#pragma unroll
  for (int j = 0; j < 8; ++j) o[j] = f2bf(v[j] * rms * wv[j]);
  *(uint4*)(xc + (size_t)ppos * DMODEL + tid * 8) = *(const uint4*)o;
}

// ---------------- RoPE in-place, row stride rstride (bf16) ----------------------
__global__ __launch_bounds__(256) void rope_k(unsigned short* __restrict__ buf,
                                              int nh, int rstride) {
  const int t = blockIdx.x;
  const int s = t & (SEQ - 1);
  const int d = threadIdx.x & 63;
  const float inv = __expf((float)d * -0.14391156843712787f);
  float sn, cs;
  __sincosf((float)s * inv, &sn, &cs);
  const int npair = nh * 64;
  for (int idx = threadIdx.x; idx < npair; idx += 256) {
    const int hh = idx >> 6;
    unsigned short* p = buf + (size_t)t * rstride + hh * 128 + d;
    const float x1 = bf2f(p[0]), x2 = bf2f(p[64]);
    p[0]  = f2bf(x1 * cs - x2 * sn);
    p[64] = f2bf(x2 * cs + x1 * sn);
  }
}

// ---------------- Flash attention, causal, GQA rep=4 (bf16 in/out) --------------
// ROUND-4 PROVEN VERSION (VGPR 104, no spill). 128-row causal pairing: block =
// (h, pair y, b) handles q-tiles qtH=15-y and qtL=y (128 rows each, 8 waves x
// 16 rows, 512 threads). Work = 34 tile-units/block, grid 512 = 2/CU. K/V staged
// once per tile (2-deep regs), shared by both contexts. Vt XOR-swizzled;
// register prefetch (T14); defer-max (T13); setprio around MFMA.
__global__ __launch_bounds__(512, 2) void attn(
    const unsigned short* __restrict__ QKV,
    unsigned short* __restrict__ O) {
  __shared__ __align__(16) unsigned short Ks[64 * 136];
  __shared__ __align__(16) unsigned short Vt[128 * 80];
  __shared__ __align__(16) unsigned short Ps[8][16 * 88];
  const int h = blockIdx.x, b = blockIdx.z;
  const int qtL = blockIdx.y, qtH = 15 - qtL;
  const int kvh = h >> 2;
  const int tid = threadIdx.x, wave = tid >> 6, lane = tid & 63;
  const int quad = lane >> 4, l16 = lane & 15;
  const int wloH = qtH * 128 + wave * 16;
  const int wloL = qtL * 128 + wave * 16;
  const int qrH = wloH + quad * 4, qrL = wloL + quad * 4;
  const float sscale = 0.08838834764831845f;  // 1/sqrt(128)

  bf16x8 qfH[4], qfL[4];
  {
    const unsigned short* qpH =
        QKV + (size_t)(b * SEQ + wloH + l16) * QKVS + h * HDIM + quad * 8;
    const unsigned short* qpL =
        QKV + (size_t)(b * SEQ + wloL + l16) * QKVS + h * HDIM + quad * 8;
#pragma unroll
    for (int c = 0; c < 4; ++c) {
      qfH[c] = *(const bf16x8*)(qpH + 32 * c);
      qfL[c] = *(const bf16x8*)(qpL + 32 * c);
    }
  }
  const floatx4 z = {0.f, 0.f, 0.f, 0.f};
  floatx4 accH[8], accL[8];
#pragma unroll
  for (int i = 0; i < 8; ++i) { accH[i] = z; accL[i] = z; }
  float mH[4], lH[4], mL[4], lL[4];
#pragma unroll
  for (int r = 0; r < 4; ++r) { mH[r] = -1e30f; lH[r] = 0.f; mL[r] = -1e30f; lL[r] = 0.f; }

  // staging coords over 512 threads: token row sr+32*it, dim cols scol..scol+7
  const int sr = tid >> 4, scol = (tid & 15) * 8;
  const unsigned short* kvb = QKV + (size_t)(b * SEQ) * QKVS + kvh * HDIM;
  uint4 kreg[2], vreg[2];

  auto LOADT = [&](int t0) {
#pragma unroll
    for (int it = 0; it < 2; ++it) {
      const int r = sr + it * 32;
      kreg[it] = *(const uint4*)(kvb + (size_t)(t0 + r) * QKVS + 2048 + scol);
      vreg[it] = *(const uint4*)(kvb + (size_t)(t0 + r) * QKVS + 2560 + scol);
    }
  };
  auto STORET = [&]() {
#pragma unroll
    for (int it = 0; it < 2; ++it) {
      const int r = sr + it * 32;
      *(uint4*)&Ks[r * 136 + scol] = kreg[it];
      const unsigned short* dv = (const unsigned short*)&vreg[it];
      const int tb = r >> 3, pos = r & 7;
#pragma unroll
      for (int j = 0; j < 8; ++j) {
        const int d = scol + j;
        const int sb = tb ^ ((d >> 3) & 7);
        Vt[d * 80 + sb * 8 + pos] = dv[j];
      }
    }
  };

  // one q-context compute step against the staged 64-token tile
  auto COMPUTE = [&](const bf16x8* qf, floatx4* accO, float* mrow, float* lrow,
                     int qrowC, int wlo, int t0) {
    floatx4 sc[4];
    __builtin_amdgcn_s_setprio(1);
#pragma unroll
    for (int ni = 0; ni < 4; ++ni) {
      floatx4 s = z;
#pragma unroll
      for (int c = 0; c < 4; ++c) {
        bf16x8 kf = *(const bf16x8*)&Ks[(ni * 16 + l16) * 136 + c * 32 + quad * 8];
        s = __builtin_amdgcn_mfma_f32_16x16x32_bf16(qf[c], kf, s, 0, 0, 0);
      }
      sc[ni] = s;
    }
    __builtin_amdgcn_s_setprio(0);

    if (t0 + 63 > wlo) {  // diagonal tile for this wave: causal mask
#pragma unroll
      for (int ni = 0; ni < 4; ++ni) {
        const int kcol = t0 + ni * 16 + l16;
#pragma unroll
        for (int reg = 0; reg < 4; ++reg) {
          const float vv = sc[ni][reg] * sscale;
          sc[ni][reg] = (kcol > qrowC + reg) ? -1e30f : vv;
        }
      }
    } else {
#pragma unroll
      for (int ni = 0; ni < 4; ++ni)
#pragma unroll
        for (int reg = 0; reg < 4; ++reg) sc[ni][reg] *= sscale;
    }

    float mx[4];
#pragma unroll
    for (int reg = 0; reg < 4; ++reg) {
      float m0 = fmaxf(fmaxf(sc[0][reg], sc[1][reg]), fmaxf(sc[2][reg], sc[3][reg]));
#pragma unroll
      for (int off = 1; off < 16; off <<= 1) m0 = fmaxf(m0, __shfl_xor(m0, off));
      mx[reg] = m0;
    }
    const bool grow = (mx[0] > mrow[0] + 8.f) || (mx[1] > mrow[1] + 8.f) ||
                      (mx[2] > mrow[2] + 8.f) || (mx[3] > mrow[3] + 8.f);
    if (__any(grow)) {
#pragma unroll
      for (int reg = 0; reg < 4; ++reg) {
        const float mnew = fmaxf(mrow[reg], mx[reg]);
        const float alpha = __expf(mrow[reg] - mnew);
        mrow[reg] = mnew;
        lrow[reg] *= alpha;
#pragma unroll
        for (int nd = 0; nd < 8; ++nd) accO[nd][reg] *= alpha;
      }
    }
#pragma unroll
    for (int reg = 0; reg < 4; ++reg) {
      float rs = 0.f;
#pragma unroll
      for (int ni = 0; ni < 4; ++ni) {
        const float p = __expf(sc[ni][reg] - mrow[reg]);
        sc[ni][reg] = p;
        rs += p;
      }
#pragma unroll
      for (int off = 1; off < 16; off <<= 1) rs += __shfl_xor(rs, off);
      lrow[reg] += rs;
    }
    // Ps is per-wave: lgkmcnt orders write->read, no barrier needed
#pragma unroll
    for (int ni = 0; ni < 4; ++ni)
#pragma unroll
      for (int reg = 0; reg < 4; ++reg)
        Ps[wave][(quad * 4 + reg) * 88 + ni * 16 + l16] = f2bf(sc[ni][reg]);
    const bf16x8 pa0 = *(const bf16x8*)&Ps[wave][l16 * 88 + quad * 8];
    const bf16x8 pa1 = *(const bf16x8*)&Ps[wave][l16 * 88 + 32 + quad * 8];
    __builtin_amdgcn_s_setprio(1);
#pragma unroll
    for (int nd = 0; nd < 8; ++nd) {
      const int d = nd * 16 + l16;
      const int f = (d >> 3) & 7;
      bf16x8 v0 = *(const bf16x8*)&Vt[d * 80 + ((quad ^ f) << 3)];
      bf16x8 v1 = *(const bf16x8*)&Vt[d * 80 + (((quad + 4) ^ f) << 3)];
      accO[nd] = __builtin_amdgcn_mfma_f32_16x16x32_bf16(pa0, v0, accO[nd], 0, 0, 0);
      accO[nd] = __builtin_amdgcn_mfma_f32_16x16x32_bf16(pa1, v1, accO[nd], 0, 0, 0);
    }
    __builtin_amdgcn_s_setprio(0);
  };

  const int ntL = 2 * qtL + 2, ntH = 2 * qtH + 2;
  LOADT(0);
  STORET();
  __syncthreads();

  for (int ti = 0; ti < ntH; ++ti) {
    const int t0 = ti * 64;
    const bool more = (ti + 1 < ntH);
    if (more) LOADT(t0 + 64);  // prefetch hides under compute

    if (t0 <= wloH + 15) COMPUTE(qfH, accH, mH, lH, qrH, wloH, t0);
    if (ti < ntL && t0 <= wloL + 15) COMPUTE(qfL, accL, mL, lL, qrL, wloL, t0);

    __syncthreads();            // all waves done reading Ks/Vt
    if (more) {
      STORET();                 // write prefetched tile
      __syncthreads();
    }
  }
#pragma unroll
  for (int nd = 0; nd < 8; ++nd)
#pragma unroll
    for (int reg = 0; reg < 4; ++reg) {
      const float oH = accH[nd][reg] / lH[reg];
      O[(size_t)(b * SEQ + qrH + reg) * (NHEAD * HDIM) + h * HDIM + nd * 16 + l16] = f2bf(oH);
      const float oL = accL[nd][reg] / lL[reg];
      O[(size_t)(b * SEQ + qrL + reg) * (NHEAD * HDIM) + h * HDIM + nd * 16 + l16] = f2bf(oL);
    }
}

// ---------------- launch --------------------------------------------------------
extern "C" void kernel_launch(void* const* d_in, const int* in_sizes, int n_in,
                              void* d_out, int out_size, void* d_ws, size_t ws_size,
                              hipStream_t stream) {
  (void)in_sizes; (void)n_in; (void)out_size; (void)ws_size;
  const float* x    = (const float*)d_in[0];
  const int*   mask = (const int*)d_in[1];
  const float* ts   = (const float*)d_in[2];
  const float* ln1  = (const float*)d_in[3];
  const float* ln2  = (const float*)d_in[4];
  const float* q_w  = (const float*)d_in[5];
  const float* k_w  = (const float*)d_in[6];
  const float* v_w  = (const float*)d_in[7];
  const float* o_w  = (const float*)d_in[8];
  const float* g_w  = (const float*)d_in[9];
  const float* u_w  = (const float*)d_in[10];
  const float* dn_w = (const float*)d_in[11];
  float* out = (float*)d_out;

  // workspace layout (h residual lives in d_out):
  // attn phase: xn [0,16.78M) | qkv [16.78,41.94) | wqkv/attno [41.94,58.72) | wo [58.72,67.11)
  // MLP phase:  xc [0,16.78M) | wg|wu [16.78,46.14) | wdn [16.78,31.46) | act [46.14,75.50)
  // meta: cnt @75.50M, tok_of @75.50M+4K
  char* ws = (char*)d_ws;
  unsigned short* xn    = (unsigned short*)(ws + 0);
  unsigned short* qkv   = (unsigned short*)(ws + 16777216);
  unsigned short* wqkv  = (unsigned short*)(ws + 41943040);
  unsigned short* attno = (unsigned short*)(ws + 41943040);  // overlays wqkv (dead)
  unsigned short* wo    = (unsigned short*)(ws + 58720256);
  unsigned short* xc    = (unsigned short*)(ws + 0);         // compacted ln2-norm rows
  unsigned short* wg    = (unsigned short*)(ws + 16777216);  // wu contiguous after wg
  unsigned short* wu    = (unsigned short*)(ws + 31457280);
  unsigned short* wdn   = (unsigned short*)(ws + 16777216);  // overlays wg (dead)
  unsigned short* act   = (unsigned short*)(ws + 46137344);  // [<=NTOK][FFH]
  int*            cnt   = (int*)           (ws + 75497472);
  int*            tok_of= (int*)           (ws + 75501568);

  // --- attention block ---
  wconv_attn<<<5120, 256, 0, stream>>>(q_w, k_w, v_w, o_w, wqkv, wo, cnt);
  rmsnorm_f32<<<NTOK, 256, 0, stream>>>(x, ln1, xn);
  gemm_bt<<<dim3(QKVS / 128, 32), 256, 0, stream>>>(xn, wqkv, qkv, QKVS, 2048);  // fused q+k+v
  rope_k<<<NTOK, 256, 0, stream>>>(qkv, 20, QKVS);  // q heads 0..15, k heads 16..19
  attn<<<dim3(NHEAD, 8, 2), 512, 0, stream>>>(qkv, attno);
  gemm_o_res<<<dim3(16, 32), 256, 0, stream>>>(attno, wo, x, out);  // out := h

  // --- MoD MLP on compacted tokens, two FF halves, scatter-add into out ---
  rms_gather<<<NTOK, 256, 0, stream>>>(out, ln2, mask, cnt, tok_of, xc);
  for (int hf = 0; hf < 2; ++hf) {
    wconv_gu<<<2 * FFH, 256, 0, stream>>>(g_w, u_w, wg, hf);  // 7168 blocks (one per row!)
    gemm_gateup<<<dim3(FFH / 64, 32), 256, 0, stream>>>(xc, wg, wu, cnt, act);
    wconv_dn<<<2048, 256, 0, stream>>>(dn_w, wdn, hf * FFH);
    gemm_down_add<<<dim3(16, 32, 2), 256, 0, stream>>>(act, wdn, ts, tok_of, cnt, out);
  }
}

// Round 8
// 892.480 us; speedup vs baseline: 1.1548x; 1.0161x over previous
//
#include <hip/hip_runtime.h>
#include <stdint.h>

#define SEQ    2048
#define DMODEL 2048
#define NTOK   4096   // B*S
#define NHEAD  16
#define NKVH   4
#define HDIM   128
#define FFDIM  7168
#define FFH    3584   // FFDIM / 2 (MLP processed in two column halves to fit workspace)
#define QKVS   3072   // merged qkv row stride: q[0,2048) k[2048,2560) v[2560,3072)

typedef __bf16 bf16x8 __attribute__((ext_vector_type(8)));
typedef float  floatx4 __attribute__((ext_vector_type(4)));

__device__ __forceinline__ float bf2f(unsigned short u) {
  union { unsigned int i; float f; } v; v.i = ((unsigned int)u) << 16; return v.f;
}
__device__ __forceinline__ unsigned short f2bf(float f) {
  union { float f; unsigned int u; } v; v.f = f;
  unsigned int r = (v.u + 0x7FFFu + ((v.u >> 16) & 1u)) >> 16;
  return (unsigned short)r;
}
// 8 f32 elements (32B) from f32 memory, converted to 8 bf16 (16B)
__device__ __forceinline__ uint4 ld8f32(const float* p) {
  float4 a = *(const float4*)p, b = *(const float4*)(p + 4);
  union { unsigned short s[8]; uint4 v; } o;
  o.s[0] = f2bf(a.x); o.s[1] = f2bf(a.y); o.s[2] = f2bf(a.z); o.s[3] = f2bf(a.w);
  o.s[4] = f2bf(b.x); o.s[5] = f2bf(b.y); o.s[6] = f2bf(b.z); o.s[7] = f2bf(b.w);
  return o.v;
}

// async HBM->LDS, 16B per lane. LDS dest = wave-uniform base + lane*16 (linear!).
__device__ __forceinline__ void gload16(const unsigned short* g, unsigned short* l) {
  __builtin_amdgcn_global_load_lds(
      (const __attribute__((address_space(1))) unsigned int*)g,
      (__attribute__((address_space(3))) unsigned int*)l, 16, 0, 0);
}

// ------- fused attn-weight + full down-weight conversion + MoD counter zero ------
// blocks 0..2047: q; 2048..2559: k; 2560..3071: v; 3072..5119: o; 5120..7167: dn.
__global__ __launch_bounds__(256) void wconv_attn(
    const float* __restrict__ q, const float* __restrict__ k,
    const float* __restrict__ v, const float* __restrict__ o,
    const float* __restrict__ dn,
    unsigned short* __restrict__ wqkv, unsigned short* __restrict__ wo,
    unsigned short* __restrict__ wdn, int* __restrict__ cnt) {
  if (blockIdx.x == 0 && threadIdx.x == 0) *cnt = 0;
  const int r = blockIdx.x;
  if (r < 5120) {
    const float* src;
    unsigned short* dst;
    if (r < 2048)      { src = q + (size_t)r * DMODEL;          dst = wqkv + (size_t)r * DMODEL; }
    else if (r < 2560) { src = k + (size_t)(r - 2048) * DMODEL; dst = wqkv + (size_t)r * DMODEL; }
    else if (r < 3072) { src = v + (size_t)(r - 2560) * DMODEL; dst = wqkv + (size_t)r * DMODEL; }
    else               { src = o + (size_t)(r - 3072) * DMODEL; dst = wo + (size_t)(r - 3072) * DMODEL; }
    const int c = threadIdx.x * 8;
    *(uint4*)(dst + c) = ld8f32(src + c);
  } else {
    const int rr = r - 5120;  // 0..2047: full down row [FFDIM]
    const float* sp = dn + (size_t)rr * FFDIM;
    unsigned short* dp = wdn + (size_t)rr * FFDIM;
    for (int c = threadIdx.x * 8; c < FFDIM; c += 2048)
      *(uint4*)(dp + c) = ld8f32(sp + c);
  }
}

// ---------------- fused gate+up conversion (dst: wg|wu contiguous) ---------------
// grid MUST be 2*FFH = 7168 blocks (one per dst row).
__global__ __launch_bounds__(256) void wconv_gu(
    const float* __restrict__ g, const float* __restrict__ u,
    unsigned short* __restrict__ dst, int hf) {
  const int r = blockIdx.x;  // 0..7167
  const float* src = (r < FFH) ? g + ((size_t)hf * FFH + r) * DMODEL
                               : u + ((size_t)hf * FFH + (r - FFH)) * DMODEL;
  const int c = threadIdx.x * 8;
  *(uint4*)(dst + (size_t)r * DMODEL + c) = ld8f32(src + c);
}

// ======== GEMM core: 128x128 tile, BK=32, 4 waves, A bf16 / W bf16 ==============
// LDA/LDB row strides, KLEN loop length, KOFF column offset (for split-K).
#define GEMM_CORE_G(Aptr, Wptr, LDA, LDB, KLEN, KOFF)                            \
  __shared__ __align__(16) unsigned short As[128 * 32];                          \
  __shared__ __align__(16) unsigned short Bs[128 * 32];                          \
  const int tid  = threadIdx.x;                                                  \
  const int wave = tid >> 6, lane = tid & 63;                                    \
  const int quad = lane >> 4, l16 = lane & 15;                                   \
  const int row0 = blockIdx.y * 128, col0 = blockIdx.x * 128;                    \
  const int wm = (wave >> 1) * 64, wn = (wave & 1) * 64;                         \
  const floatx4 z = {0.f, 0.f, 0.f, 0.f};                                       \
  floatx4 acc[4][4];                                                             \
  _Pragma("unroll") for (int i = 0; i < 4; ++i)                                  \
  _Pragma("unroll") for (int j = 0; j < 4; ++j) acc[i][j] = z;                   \
  const int ar0 = tid >> 2, ac0 = (tid & 3) << 3;                                \
  unsigned short* lA0 = &As[wave * 512];                                         \
  unsigned short* lA1 = &As[2048 + wave * 512];                                  \
  unsigned short* lB0 = &Bs[wave * 512];                                         \
  unsigned short* lB1 = &Bs[2048 + wave * 512];                                  \
  const unsigned short* gA0 = (Aptr) + (size_t)(row0 + ar0) * (LDA) + (KOFF) + ac0;      \
  const unsigned short* gA1 = (Aptr) + (size_t)(row0 + 64 + ar0) * (LDA) + (KOFF) + ac0; \
  const unsigned short* gB0 = (Wptr) + (size_t)(col0 + ar0) * (LDB) + (KOFF) + ac0;      \
  const unsigned short* gB1 = (Wptr) + (size_t)(col0 + 64 + ar0) * (LDB) + (KOFF) + ac0; \
  for (int k0 = 0; k0 < (KLEN); k0 += 32) {                                      \
    gload16(gA0 + k0, lA0);                                                      \
    gload16(gA1 + k0, lA1);                                                      \
    gload16(gB0 + k0, lB0);                                                      \
    gload16(gB1 + k0, lB1);                                                      \
    __syncthreads();                                                             \
    bf16x8 af[4], bfr[4];                                                        \
    _Pragma("unroll") for (int i = 0; i < 4; ++i) {                              \
      af[i]  = *(const bf16x8*)&As[(wm + i * 16 + l16) * 32 + quad * 8];         \
      bfr[i] = *(const bf16x8*)&Bs[(wn + i * 16 + l16) * 32 + quad * 8];         \
    }                                                                            \
    _Pragma("unroll") for (int mi = 0; mi < 4; ++mi)                             \
    _Pragma("unroll") for (int ni = 0; ni < 4; ++ni)                             \
      acc[mi][ni] =                                                              \
          __builtin_amdgcn_mfma_f32_16x16x32_bf16(af[mi], bfr[ni], acc[mi][ni], 0, 0, 0); \
    __syncthreads();                                                             \
  }

// C[M,N] = A[M,K] * W[N,K]^T, all bf16
__global__ __launch_bounds__(256) void gemm_bt(
    const unsigned short* __restrict__ A, const unsigned short* __restrict__ W,
    unsigned short* __restrict__ C, int N, int K) {
  GEMM_CORE_G(A, W, K, K, K, 0)
#pragma unroll
  for (int mi = 0; mi < 4; ++mi) {
    const int r = row0 + wm + mi * 16 + quad * 4;
#pragma unroll
    for (int ni = 0; ni < 4; ++ni) {
      const int cc = col0 + wn + ni * 16 + l16;
#pragma unroll
      for (int reg = 0; reg < 4; ++reg)
        C[(size_t)(r + reg) * N + cc] = f2bf(acc[mi][ni][reg]);
    }
  }
}

// o-proj + residual: out (f32) = x (f32) + A*W^T   (h lives in d_out)
__global__ __launch_bounds__(256) void gemm_o_res(
    const unsigned short* __restrict__ A, const unsigned short* __restrict__ W,
    const float* __restrict__ X, float* __restrict__ Hout) {
  GEMM_CORE_G(A, W, DMODEL, DMODEL, DMODEL, 0)
#pragma unroll
  for (int mi = 0; mi < 4; ++mi) {
    const int r = row0 + wm + mi * 16 + quad * 4;
#pragma unroll
    for (int ni = 0; ni < 4; ++ni) {
      const int cc = col0 + wn + ni * 16 + l16;
#pragma unroll
      for (int reg = 0; reg < 4; ++reg) {
        const size_t idx = (size_t)(r + reg) * DMODEL + cc;
        Hout[idx] = X[idx] + acc[mi][ni][reg];
      }
    }
  }
}

// down-proj on COMPACTED rows, split-K over blockIdx.z, MoD scatter atomicAdd.
// A = act [rows][FFH]; W = wdn (+hf*FFH col base), row stride FFDIM.
__global__ __launch_bounds__(256) void gemm_down_add(
    const unsigned short* __restrict__ A, const unsigned short* __restrict__ W,
    const float* __restrict__ ts, const int* __restrict__ tok_of,
    const int* __restrict__ cnt, float* __restrict__ out) {
  const int nrow = *cnt;
  if (blockIdx.y * 128 >= nrow) return;
  const int koff = blockIdx.z * (FFH / 2);
  GEMM_CORE_G(A, W, FFH, FFDIM, FFH / 2, koff)
#pragma unroll
  for (int mi = 0; mi < 4; ++mi) {
    const int r = row0 + wm + mi * 16 + quad * 4;
#pragma unroll
    for (int ni = 0; ni < 4; ++ni) {
      const int cc = col0 + wn + ni * 16 + l16;
#pragma unroll
      for (int reg = 0; reg < 4; ++reg) {
        const int rr = r + reg;
        if (rr < nrow) {
          const int tok = tok_of[rr];
          const float scv = 0.5f + (ts[tok] - 0.5f) * 0.7f;
          atomicAdd(out + (size_t)tok * DMODEL + cc, acc[mi][ni][reg] * scv);
        }
      }
    }
  }
}

// fused gate+up GEMM on COMPACTED rows with silu(g)*u epilogue. 128 rows x 64 cols.
__global__ __launch_bounds__(256) void gemm_gateup(
    const unsigned short* __restrict__ A, const unsigned short* __restrict__ G,
    const unsigned short* __restrict__ U, const int* __restrict__ cnt,
    unsigned short* __restrict__ act) {
  if (blockIdx.y * 128 >= *cnt) return;
  __shared__ __align__(16) unsigned short As[128 * 32];
  __shared__ __align__(16) unsigned short Gs[64 * 32];
  __shared__ __align__(16) unsigned short Us[64 * 32];
  const int tid  = threadIdx.x;
  const int wave = tid >> 6, lane = tid & 63;
  const int quad = lane >> 4, l16 = lane & 15;
  const int row0 = blockIdx.y * 128, colg = blockIdx.x * 64;
  const int wm = (wave >> 1) * 64, wn = (wave & 1) * 32;

  const floatx4 z = {0.f, 0.f, 0.f, 0.f};
  floatx4 accG[4][2], accU[4][2];
#pragma unroll
  for (int i = 0; i < 4; ++i)
#pragma unroll
    for (int j = 0; j < 2; ++j) { accG[i][j] = z; accU[i][j] = z; }

  const int ar0 = tid >> 2, ac0 = (tid & 3) << 3;
  unsigned short* lA0 = &As[wave * 512];
  unsigned short* lA1 = &As[2048 + wave * 512];
  unsigned short* lG  = &Gs[wave * 512];
  unsigned short* lU  = &Us[wave * 512];
  const unsigned short* gA0 = A + (size_t)(row0 + ar0) * DMODEL + ac0;
  const unsigned short* gA1 = A + (size_t)(row0 + 64 + ar0) * DMODEL + ac0;
  const unsigned short* gG  = G + (size_t)(colg + ar0) * DMODEL + ac0;
  const unsigned short* gU  = U + (size_t)(colg + ar0) * DMODEL + ac0;

  for (int k0 = 0; k0 < DMODEL; k0 += 32) {
    gload16(gA0 + k0, lA0);
    gload16(gA1 + k0, lA1);
    gload16(gG + k0, lG);
    gload16(gU + k0, lU);
    __syncthreads();
    bf16x8 af[4], bg[2], bu[2];
#pragma unroll
    for (int i = 0; i < 4; ++i)
      af[i] = *(const bf16x8*)&As[(wm + i * 16 + l16) * 32 + quad * 8];
#pragma unroll
    for (int j = 0; j < 2; ++j) {
      bg[j] = *(const bf16x8*)&Gs[(wn + j * 16 + l16) * 32 + quad * 8];
      bu[j] = *(const bf16x8*)&Us[(wn + j * 16 + l16) * 32 + quad * 8];
    }
#pragma unroll
    for (int mi = 0; mi < 4; ++mi)
#pragma unroll
      for (int ni = 0; ni < 2; ++ni) {
        accG[mi][ni] = __builtin_amdgcn_mfma_f32_16x16x32_bf16(af[mi], bg[ni], accG[mi][ni], 0, 0, 0);
        accU[mi][ni] = __builtin_amdgcn_mfma_f32_16x16x32_bf16(af[mi], bu[ni], accU[mi][ni], 0, 0, 0);
      }
    __syncthreads();
  }
#pragma unroll
  for (int mi = 0; mi < 4; ++mi) {
    const int r = row0 + wm + mi * 16 + quad * 4;
#pragma unroll
    for (int ni = 0; ni < 2; ++ni) {
      const int cc = colg + wn + ni * 16 + l16;
#pragma unroll
      for (int reg = 0; reg < 4; ++reg) {
        const float g = accG[mi][ni][reg];
        const float u = accU[mi][ni][reg];
        const float s = g / (1.f + __expf(-g));
        act[(size_t)(r + reg) * FFH + cc] = f2bf(s * u);
      }
    }
  }
}

// ---------------- RMSNorm (ln1): f32 in, f32 weight, bf16 out --------------------
__global__ __launch_bounds__(256) void rmsnorm_f32(
    const float* __restrict__ x, const float* __restrict__ w,
    unsigned short* __restrict__ out) {
  __shared__ float red[4];
  const int row = blockIdx.x, tid = threadIdx.x;
  const int lane = tid & 63, wave = tid >> 6;
  const size_t base = (size_t)row * DMODEL + tid * 8;
  float4 a = *(const float4*)(x + base);
  float4 b = *(const float4*)(x + base + 4);
  float v[8] = {a.x, a.y, a.z, a.w, b.x, b.y, b.z, b.w};
  float ss = 0.f;
#pragma unroll
  for (int j = 0; j < 8; ++j) ss += v[j] * v[j];
#pragma unroll
  for (int off = 32; off; off >>= 1) ss += __shfl_xor(ss, off);
  if (lane == 0) red[wave] = ss;
  __syncthreads();
  const float tot = red[0] + red[1] + red[2] + red[3];
  const float rms = rsqrtf(tot * (1.f / (float)DMODEL) + 1e-5f);
  float4 wa = *(const float4*)(w + tid * 8);
  float4 wb = *(const float4*)(w + tid * 8 + 4);
  const float wv[8] = {wa.x, wa.y, wa.z, wa.w, wb.x, wb.y, wb.z, wb.w};
  unsigned short o[8];
#pragma unroll
  for (int j = 0; j < 8; ++j) o[j] = f2bf(v[j] * rms * wv[j]);
  *(uint4*)(out + base) = *(const uint4*)o;
}

// ---------------- RMSNorm (ln2) + MoD compaction gather --------------------------
__global__ __launch_bounds__(256) void rms_gather(
    const float* __restrict__ x, const float* __restrict__ w,
    const int* __restrict__ mask, int* __restrict__ cnt,
    int* __restrict__ tok_of, unsigned short* __restrict__ xc) {
  const int row = blockIdx.x;
  if (!mask[row]) return;
  __shared__ float red[4];
  __shared__ int ppos;
  const int tid = threadIdx.x, lane = tid & 63, wave = tid >> 6;
  if (tid == 0) { const int p = atomicAdd(cnt, 1); ppos = p; tok_of[p] = row; }
  const size_t base = (size_t)row * DMODEL + tid * 8;
  float4 a = *(const float4*)(x + base);
  float4 b = *(const float4*)(x + base + 4);
  float v[8] = {a.x, a.y, a.z, a.w, b.x, b.y, b.z, b.w};
  float ss = 0.f;
#pragma unroll
  for (int j = 0; j < 8; ++j) ss += v[j] * v[j];
#pragma unroll
  for (int off = 32; off; off >>= 1) ss += __shfl_xor(ss, off);
  if (lane == 0) red[wave] = ss;
  __syncthreads();  // covers red[] and ppos
  const float tot = red[0] + red[1] + red[2] + red[3];
  const float rms = rsqrtf(tot * (1.f / (float)DMODEL) + 1e-5f);
  float4 wa = *(const float4*)(w + tid * 8);
  float4 wb = *(const float4*)(w + tid * 8 + 4);
  const float wv[8] = {wa.x, wa.y, wa.z, wa.w, wb.x, wb.y, wb.z, wb.w};
  unsigned short o[8];
#pragma unroll
  for (int j = 0; j < 8; ++j) o[j] = f2bf(v[j] * rms * wv[j]);
  *(uint4*)(xc + (size_t)ppos * DMODEL + tid * 8) = *(const uint4*)o;
}

// ---------------- RoPE in-place, row stride rstride (bf16) ----------------------
__global__ __launch_bounds__(256) void rope_k(unsigned short* __restrict__ buf,
                                              int nh, int rstride) {
  const int t = blockIdx.x;
  const int s = t & (SEQ - 1);
  const int d = threadIdx.x & 63;
  const float inv = __expf((float)d * -0.14391156843712787f);
  float sn, cs;
  __sincosf((float)s * inv, &sn, &cs);
  const int npair = nh * 64;
  for (int idx = threadIdx.x; idx < npair; idx += 256) {
    const int hh = idx >> 6;
    unsigned short* p = buf + (size_t)t * rstride + hh * 128 + d;
    const float x1 = bf2f(p[0]), x2 = bf2f(p[64]);
    p[0]  = f2bf(x1 * cs - x2 * sn);
    p[64] = f2bf(x2 * cs + x1 * sn);
  }
}

// ---------------- Flash attention, causal, GQA rep=4 (bf16 in/out) --------------
// Round-4 structure (512 thr, 128-row pairing, VGPR-safe) + FUSED K/V-read
// sharing: when both paired contexts are active for a tile, one kf/v read feeds
// both contexts' MFMAs (ds_read_b128 68 -> 36 per wave-tile). qfL is reloaded
// from global (L1/L2-hot) per fused tile to keep VGPR <= 128. SOLO(L) is
// unreachable (aL => aH); H is never diagonal inside a fused tile.
__global__ __launch_bounds__(512, 2) void attn(
    const unsigned short* __restrict__ QKV,
    unsigned short* __restrict__ O) {
  __shared__ __align__(16) unsigned short Ks[64 * 136];
  __shared__ __align__(16) unsigned short Vt[128 * 80];
  __shared__ __align__(16) unsigned short Ps[8][16 * 88];
  const int h = blockIdx.x, b = blockIdx.z;
  const int qtL = blockIdx.y, qtH = 15 - qtL;
  const int kvh = h >> 2;
  const int tid = threadIdx.x, wave = tid >> 6, lane = tid & 63;
  const int quad = lane >> 4, l16 = lane & 15;
  const int wloH = qtH * 128 + wave * 16;
  const int wloL = qtL * 128 + wave * 16;
  const int qrH = wloH + quad * 4, qrL = wloL + quad * 4;
  const float sscale = 0.08838834764831845f;  // 1/sqrt(128)

  const unsigned short* qpL =
      QKV + (size_t)(b * SEQ + wloL + l16) * QKVS + h * HDIM + quad * 8;
  bf16x8 qfH[4];
  {
    const unsigned short* qpH =
        QKV + (size_t)(b * SEQ + wloH + l16) * QKVS + h * HDIM + quad * 8;
#pragma unroll
    for (int c = 0; c < 4; ++c) qfH[c] = *(const bf16x8*)(qpH + 32 * c);
  }
  const floatx4 z = {0.f, 0.f, 0.f, 0.f};
  floatx4 accH[8], accL[8];
#pragma unroll
  for (int i = 0; i < 8; ++i) { accH[i] = z; accL[i] = z; }
  float mH[4], lH[4], mL[4], lL[4];
#pragma unroll
  for (int r = 0; r < 4; ++r) { mH[r] = -1e30f; lH[r] = 0.f; mL[r] = -1e30f; lL[r] = 0.f; }

  // staging coords over 512 threads: token row sr+32*it, dim cols scol..scol+7
  const int sr = tid >> 4, scol = (tid & 15) * 8;
  const unsigned short* kvb = QKV + (size_t)(b * SEQ) * QKVS + kvh * HDIM;
  uint4 kreg[2], vreg[2];

  auto LOADT = [&](int t0) {
#pragma unroll
    for (int it = 0; it < 2; ++it) {
      const int r = sr + it * 32;
      kreg[it] = *(const uint4*)(kvb + (size_t)(t0 + r) * QKVS + 2048 + scol);
      vreg[it] = *(const uint4*)(kvb + (size_t)(t0 + r) * QKVS + 2560 + scol);
    }
  };
  auto STORET = [&]() {
#pragma unroll
    for (int it = 0; it < 2; ++it) {
      const int r = sr + it * 32;
      *(uint4*)&Ks[r * 136 + scol] = kreg[it];
      const unsigned short* dv = (const unsigned short*)&vreg[it];
      const int tb = r >> 3, pos = r & 7;
#pragma unroll
      for (int j = 0; j < 8; ++j) {
        const int d = scol + j;
        const int sb = tb ^ ((d >> 3) & 7);
        Vt[d * 80 + sb * 8 + pos] = dv[j];
      }
    }
  };

  // softmax + P->A-fragment for one context; sc in [post-mask, scaled] form.
  auto SOFTPA = [&](floatx4* sc, float* mrow, float* lrow, floatx4* accO,
                    bf16x8& pa0, bf16x8& pa1) {
    float mx[4];
#pragma unroll
    for (int reg = 0; reg < 4; ++reg) {
      float m0 = fmaxf(fmaxf(sc[0][reg], sc[1][reg]), fmaxf(sc[2][reg], sc[3][reg]));
#pragma unroll
      for (int off = 1; off < 16; off <<= 1) m0 = fmaxf(m0, __shfl_xor(m0, off));
      mx[reg] = m0;
    }
    const bool grow = (mx[0] > mrow[0] + 8.f) || (mx[1] > mrow[1] + 8.f) ||
                      (mx[2] > mrow[2] + 8.f) || (mx[3] > mrow[3] + 8.f);
    if (__any(grow)) {
#pragma unroll
      for (int reg = 0; reg < 4; ++reg) {
        const float mnew = fmaxf(mrow[reg], mx[reg]);
        const float alpha = __expf(mrow[reg] - mnew);
        mrow[reg] = mnew;
        lrow[reg] *= alpha;
#pragma unroll
        for (int nd = 0; nd < 8; ++nd) accO[nd][reg] *= alpha;
      }
    }
#pragma unroll
    for (int reg = 0; reg < 4; ++reg) {
      float rs = 0.f;
#pragma unroll
      for (int ni = 0; ni < 4; ++ni) {
        const float p = __expf(sc[ni][reg] - mrow[reg]);
        sc[ni][reg] = p;
        rs += p;
      }
#pragma unroll
      for (int off = 1; off < 16; off <<= 1) rs += __shfl_xor(rs, off);
      lrow[reg] += rs;
    }
    // Ps is per-wave scratch: compiler-inserted lgkmcnt orders write->read
#pragma unroll
    for (int ni = 0; ni < 4; ++ni)
#pragma unroll
      for (int reg = 0; reg < 4; ++reg)
        Ps[wave][(quad * 4 + reg) * 88 + ni * 16 + l16] = f2bf(sc[ni][reg]);
    pa0 = *(const bf16x8*)&Ps[wave][l16 * 88 + quad * 8];
    pa1 = *(const bf16x8*)&Ps[wave][l16 * 88 + 32 + quad * 8];
  };

  const int ntL = 2 * qtL + 2, ntH = 2 * qtH + 2;
  LOADT(0);
  STORET();
  __syncthreads();

  for (int ti = 0; ti < ntH; ++ti) {
    const int t0 = ti * 64;
    const bool more = (ti + 1 < ntH);
    if (more) LOADT(t0 + 64);  // prefetch hides under compute

    const bool aH = (t0 <= wloH + 15);
    const bool aL = (ti < ntL) && (t0 <= wloL + 15);

    if (aL) {
      // ---- FUSED: H and L share every Ks/Vt fragment read ----
      bf16x8 qfLt[4];
#pragma unroll
      for (int c = 0; c < 4; ++c) qfLt[c] = *(const bf16x8*)(qpL + 32 * c);
      floatx4 sH[4], sL[4];
      __builtin_amdgcn_s_setprio(1);
#pragma unroll
      for (int ni = 0; ni < 4; ++ni) {
        floatx4 a = z, bb = z;
#pragma unroll
        for (int c = 0; c < 4; ++c) {
          bf16x8 kf = *(const bf16x8*)&Ks[(ni * 16 + l16) * 136 + c * 32 + quad * 8];
          a  = __builtin_amdgcn_mfma_f32_16x16x32_bf16(qfH[c], kf, a, 0, 0, 0);
          bb = __builtin_amdgcn_mfma_f32_16x16x32_bf16(qfLt[c], kf, bb, 0, 0, 0);
        }
        sH[ni] = a; sL[ni] = bb;
      }
      __builtin_amdgcn_s_setprio(0);
      // H is never diagonal in the fused range (t0+63 < wloH): plain scale
#pragma unroll
      for (int ni = 0; ni < 4; ++ni)
#pragma unroll
        for (int reg = 0; reg < 4; ++reg) sH[ni][reg] *= sscale;
      if (t0 + 63 > wloL) {  // L diagonal tile: causal mask
#pragma unroll
        for (int ni = 0; ni < 4; ++ni) {
          const int kcol = t0 + ni * 16 + l16;
#pragma unroll
          for (int reg = 0; reg < 4; ++reg) {
            const float vv = sL[ni][reg] * sscale;
            sL[ni][reg] = (kcol > qrL + reg) ? -1e30f : vv;
          }
        }
      } else {
#pragma unroll
        for (int ni = 0; ni < 4; ++ni)
#pragma unroll
          for (int reg = 0; reg < 4; ++reg) sL[ni][reg] *= sscale;
      }
      bf16x8 paH0, paH1, paL0, paL1;
      SOFTPA(sH, mH, lH, accH, paH0, paH1);
      SOFTPA(sL, mL, lL, accL, paL0, paL1);
      __builtin_amdgcn_s_setprio(1);
#pragma unroll
      for (int nd = 0; nd < 8; ++nd) {
        const int d = nd * 16 + l16;
        const int f = (d >> 3) & 7;
        bf16x8 v0 = *(const bf16x8*)&Vt[d * 80 + ((quad ^ f) << 3)];
        bf16x8 v1 = *(const bf16x8*)&Vt[d * 80 + (((quad + 4) ^ f) << 3)];
        accH[nd] = __builtin_amdgcn_mfma_f32_16x16x32_bf16(paH0, v0, accH[nd], 0, 0, 0);
        accH[nd] = __builtin_amdgcn_mfma_f32_16x16x32_bf16(paH1, v1, accH[nd], 0, 0, 0);
        accL[nd] = __builtin_amdgcn_mfma_f32_16x16x32_bf16(paL0, v0, accL[nd], 0, 0, 0);
        accL[nd] = __builtin_amdgcn_mfma_f32_16x16x32_bf16(paL1, v1, accL[nd], 0, 0, 0);
      }
      __builtin_amdgcn_s_setprio(0);
    } else if (aH) {
      // ---- SOLO H (original proven path) ----
      floatx4 sc[4];
      __builtin_amdgcn_s_setprio(1);
#pragma unroll
      for (int ni = 0; ni < 4; ++ni) {
        floatx4 s = z;
#pragma unroll
        for (int c = 0; c < 4; ++c) {
          bf16x8 kf = *(const bf16x8*)&Ks[(ni * 16 + l16) * 136 + c * 32 + quad * 8];
          s = __builtin_amdgcn_mfma_f32_16x16x32_bf16(qfH[c], kf, s, 0, 0, 0);
        }
        sc[ni] = s;
      }
      __builtin_amdgcn_s_setprio(0);
      if (t0 + 63 > wloH) {
#pragma unroll
        for (int ni = 0; ni < 4; ++ni) {
          const int kcol = t0 + ni * 16 + l16;
#pragma unroll
          for (int reg = 0; reg < 4; ++reg) {
            const float vv = sc[ni][reg] * sscale;
            sc[ni][reg] = (kcol > qrH + reg) ? -1e30f : vv;
          }
        }
      } else {
#pragma unroll
        for (int ni = 0; ni < 4; ++ni)
#pragma unroll
          for (int reg = 0; reg < 4; ++reg) sc[ni][reg] *= sscale;
      }
      bf16x8 pa0, pa1;
      SOFTPA(sc, mH, lH, accH, pa0, pa1);
      __builtin_amdgcn_s_setprio(1);
#pragma unroll
      for (int nd = 0; nd < 8; ++nd) {
        const int d = nd * 16 + l16;
        const int f = (d >> 3) & 7;
        bf16x8 v0 = *(const bf16x8*)&Vt[d * 80 + ((quad ^ f) << 3)];
        bf16x8 v1 = *(const bf16x8*)&Vt[d * 80 + (((quad + 4) ^ f) << 3)];
        accH[nd] = __builtin_amdgcn_mfma_f32_16x16x32_bf16(pa0, v0, accH[nd], 0, 0, 0);
        accH[nd] = __builtin_amdgcn_mfma_f32_16x16x32_bf16(pa1, v1, accH[nd], 0, 0, 0);
      }
      __builtin_amdgcn_s_setprio(0);
    }

    __syncthreads();            // all waves done reading Ks/Vt
    if (more) {
      STORET();                 // write prefetched tile
      __syncthreads();
    }
  }
#pragma unroll
  for (int nd = 0; nd < 8; ++nd)
#pragma unroll
    for (int reg = 0; reg < 4; ++reg) {
      const float oH = accH[nd][reg] / lH[reg];
      O[(size_t)(b * SEQ + qrH + reg) * (NHEAD * HDIM) + h * HDIM + nd * 16 + l16] = f2bf(oH);
      const float oL = accL[nd][reg] / lL[reg];
      O[(size_t)(b * SEQ + qrL + reg) * (NHEAD * HDIM) + h * HDIM + nd * 16 + l16] = f2bf(oL);
    }
}

// ---------------- launch --------------------------------------------------------
extern "C" void kernel_launch(void* const* d_in, const int* in_sizes, int n_in,
                              void* d_out, int out_size, void* d_ws, size_t ws_size,
                              hipStream_t stream) {
  (void)in_sizes; (void)n_in; (void)out_size; (void)ws_size;
  const float* x    = (const float*)d_in[0];
  const int*   mask = (const int*)d_in[1];
  const float* ts   = (const float*)d_in[2];
  const float* ln1  = (const float*)d_in[3];
  const float* ln2  = (const float*)d_in[4];
  const float* q_w  = (const float*)d_in[5];
  const float* k_w  = (const float*)d_in[6];
  const float* v_w  = (const float*)d_in[7];
  const float* o_w  = (const float*)d_in[8];
  const float* g_w  = (const float*)d_in[9];
  const float* u_w  = (const float*)d_in[10];
  const float* dn_w = (const float*)d_in[11];
  float* out = (float*)d_out;

  // workspace layout (h residual lives in d_out):
  // attn phase: xn [0,16.78M) | qkv [16.78,41.94) | wqkv/attno [41.94,58.72) | wo [58.72,67.11)
  // MLP phase:  xc [0,16.78M) | wg|wu [16.78,46.14) | act [46.14,75.50)
  // persistent: wdn full [75.50,104.86) | cnt @104.86M | tok_of after
  char* ws = (char*)d_ws;
  unsigned short* xn    = (unsigned short*)(ws + 0);
  unsigned short* qkv   = (unsigned short*)(ws + 16777216);
  unsigned short* wqkv  = (unsigned short*)(ws + 41943040);
  unsigned short* attno = (unsigned short*)(ws + 41943040);  // overlays wqkv (dead)
  unsigned short* wo    = (unsigned short*)(ws + 58720256);
  unsigned short* xc    = (unsigned short*)(ws + 0);         // compacted ln2-norm rows
  unsigned short* wg    = (unsigned short*)(ws + 16777216);  // wu contiguous after wg
  unsigned short* wu    = (unsigned short*)(ws + 31457280);
  unsigned short* act   = (unsigned short*)(ws + 46137344);  // [<=NTOK][FFH]
  unsigned short* wdn   = (unsigned short*)(ws + 75497472);  // full [2048][FFDIM]
  int*            cnt   = (int*)           (ws + 104857600);
  int*            tok_of= (int*)           (ws + 104857608);

  // --- attention block (+ full down-weight conversion upfront) ---
  wconv_attn<<<7168, 256, 0, stream>>>(q_w, k_w, v_w, o_w, dn_w, wqkv, wo, wdn, cnt);
  rmsnorm_f32<<<NTOK, 256, 0, stream>>>(x, ln1, xn);
  gemm_bt<<<dim3(QKVS / 128, 32), 256, 0, stream>>>(xn, wqkv, qkv, QKVS, 2048);  // fused q+k+v
  rope_k<<<NTOK, 256, 0, stream>>>(qkv, 20, QKVS);  // q heads 0..15, k heads 16..19
  attn<<<dim3(NHEAD, 8, 2), 512, 0, stream>>>(qkv, attno);
  gemm_o_res<<<dim3(16, 32), 256, 0, stream>>>(attno, wo, x, out);  // out := h

  // --- MoD MLP on compacted tokens, two FF halves, scatter-add into out ---
  rms_gather<<<NTOK, 256, 0, stream>>>(out, ln2, mask, cnt, tok_of, xc);
  for (int hf = 0; hf < 2; ++hf) {
    wconv_gu<<<2 * FFH, 256, 0, stream>>>(g_w, u_w, wg, hf);  // 7168 blocks (one per row)
    gemm_gateup<<<dim3(FFH / 64, 32), 256, 0, stream>>>(xc, wg, wu, cnt, act);
    gemm_down_add<<<dim3(16, 32, 2), 256, 0, stream>>>(act, wdn + (size_t)hf * FFH,
                                                       ts, tok_of, cnt, out);
  }
}